// Round 6
// baseline (1786.787 us; speedup 1.0000x reference)
//
#include <hip/hip_runtime.h>
#include <hip/hip_bf16.h>

// 4-layer SRU. L=4, B=32, T=512, D=512, V=1000. f32 inputs, f32 output.
// R5: scan de-latency: U stored interleaved as float4 (xt,fp,rp,-) so the
// scan does ONE dwordx4 + ONE dword load per step; __launch_bounds__(64,1)
// so the 8-deep prefetch pipeline actually gets registers. GEMM epilogue
// writes the interleaved layout (stride-16B scalar stores, off critical path).

#define LAYERS 4
#define BB 32
#define TT 512
#define DD 512
#define N3 1536
#define MROWS (TT * BB)
#define WPL ((size_t)DD * N3)   // 786432 elems per layer ([n][k] = 1536*512)
#define PF 8

typedef unsigned short u16;
typedef short bshort8 __attribute__((ext_vector_type(8)));
typedef unsigned short ushort8v __attribute__((ext_vector_type(8)));
typedef float f32x4 __attribute__((ext_vector_type(4)));

__device__ __forceinline__ float b2f(u16 u) {
  union { unsigned int i; float f; } x;
  x.i = ((unsigned int)u) << 16;
  return x.f;
}
__device__ __forceinline__ u16 f2b(float f) {  // RNE
  union { float f; unsigned int i; } x;
  x.f = f;
  unsigned int r = (x.i + 0x7FFFu + ((x.i >> 16) & 1u)) >> 16;
  return (u16)r;
}

// ---- dtype detection (flags[0]: floats f32, [1]: mask bytes, [2]: ids int64)
__global__ void detect_kernel(const u16* __restrict__ emb_u,
                              const int* __restrict__ mask_i,
                              const int* __restrict__ ids_i,
                              int* __restrict__ flags) {
  __shared__ int cnt[3];
  __shared__ int zc;
  int tid = threadIdx.x;
  if (tid < 3) cnt[tid] = 0;
  if (tid == 0) zc = 0;
  __syncthreads();
  int bad = 0, zero_even = 0;
  for (int i = tid; i < 8192; i += 256) {
    u16 u = emb_u[i];
    unsigned e = (u >> 7) & 0xFF;
    if (e >= 0x8F) bad++;
    if ((i & 1) == 0 && u == 0) zero_even++;
  }
  if (bad) atomicAdd(&cnt[0], bad);
  if (zero_even) atomicAdd(&zc, zero_even);
  if (tid < 64) {
    unsigned vv = (unsigned)mask_i[tid];
    if (vv > 1u) atomicAdd(&cnt[1], 1);
  }
  if (tid < 256) {
    if (ids_i[2 * tid + 1] == 0) atomicAdd(&cnt[2], 1);
  }
  __syncthreads();
  if (tid == 0) {
    flags[0] = (cnt[0] > 64 || zc > 3000) ? 1 : 0;
    flags[1] = (cnt[1] > 0) ? 1 : 0;
    flags[2] = (cnt[2] >= 192) ? 1 : 0;
  }
}

// ---- W split+transpose: Wst[l][s][n][k] bf16, s=0 hi, s=1 lo -----------
__global__ __launch_bounds__(256)
void wprep_kernel(const void* __restrict__ W, u16* __restrict__ Wst,
                  const int* __restrict__ flags) {
  __shared__ float tileW[32][33];
  int l = blockIdx.z;
  int k0 = blockIdx.x * 32;
  int n0 = blockIdx.y * 32;
  int tx = threadIdx.x & 31;
  int ty = threadIdx.x >> 5;  // 0..7
  int ff = flags[0];
  const float* Wf = (const float*)W + (size_t)l * WPL;
  const u16* Wb = (const u16*)W + (size_t)l * WPL;
  for (int kk = ty; kk < 32; kk += 8) {
    size_t off = (size_t)(k0 + kk) * N3 + n0 + tx;
    tileW[kk][tx] = ff ? Wf[off] : b2f(Wb[off]);
  }
  __syncthreads();
  u16* hiP = Wst + (size_t)l * 2 * WPL;
  u16* loP = hiP + WPL;
  for (int nn = ty; nn < 32; nn += 8) {
    float x = tileW[tx][nn];
    u16 hi = f2b(x);
    u16 lo = f2b(x - b2f(hi));
    size_t o = (size_t)(n0 + nn) * DD + k0 + tx;
    hiP[o] = hi;
    loP[o] = lo;
  }
}

// ---- embedding: X f32 (B,T,D) = d_out; Xh/Xl bf16 (T,B,D) --------------
__global__ void embed_kernel(const int* __restrict__ ids,
                             const void* __restrict__ emb,
                             float* __restrict__ X,
                             u16* __restrict__ Xh, u16* __restrict__ Xl,
                             const int* __restrict__ flags) {
  int i = blockIdx.x * 256 + threadIdx.x;  // (t,b,d) linear
  int d = i & (DD - 1);
  int tb = i >> 9;
  int b = tb & (BB - 1);
  int t = tb >> 5;
  int ii = b * TT + t;
  int id = flags[2] ? ids[2 * ii] : ids[ii];
  float val = flags[0] ? ((const float*)emb)[id * DD + d]
                       : b2f(((const u16*)emb)[id * DD + d]);
  X[((size_t)b * TT + t) * DD + d] = val;
  u16 hi = f2b(val);
  Xh[i] = hi;
  Xl[i] = f2b(val - b2f(hi));
}

// ---- MFMA GEMM: U4[r][d][p] (p=0 xt,1 fpre,2 rpre) = split X * W_l -----
// virtual K=1536: pass0 Xh*Wh, pass1 Xh*Wl, pass2 Xl*Wh. 128x128 tile,
// 4 waves (2x2 of 64x64), 16x16x32 bf16 MFMA, LDS stride 40.
__global__ __launch_bounds__(256)
void gemm_kernel(const u16* __restrict__ Xh, const u16* __restrict__ Xl,
                 const u16* __restrict__ Ws,  // layer base [2][1536][512]
                 float* __restrict__ U4, int row_base) {
  __shared__ u16 At[128][40];
  __shared__ u16 Bt[128][40];
  const int tid = threadIdx.x;
  const int row0 = blockIdx.x * 128;
  const int col0 = blockIdx.y * 128;
  const int lane = tid & 63, wave = tid >> 6;
  const int wm = (wave >> 1) * 64, wn = (wave & 1) * 64;
  const int m16 = lane & 15, quad = lane >> 4;
  const int srow = tid >> 1;
  const int sk0 = (tid & 1) * 16;

  f32x4 acc[4][4];
#pragma unroll
  for (int mi = 0; mi < 4; ++mi)
#pragma unroll
    for (int ni = 0; ni < 4; ++ni)
#pragma unroll
      for (int r = 0; r < 4; ++r) acc[mi][ni][r] = 0.f;

  for (int kv = 0; kv < 1536; kv += 32) {
    int p = kv >> 9;
    int k0 = kv & 511;
    const u16* Asrc = (p == 2) ? Xl : Xh;
    const u16* Bsrc = Ws + ((p == 1) ? WPL : 0);

    size_t abase = (size_t)(row_base + row0 + srow) * DD + k0 + sk0;
    ushort8v a0 = *(const ushort8v*)(Asrc + abase);
    ushort8v a1 = *(const ushort8v*)(Asrc + abase + 8);
    size_t bbase = (size_t)(col0 + srow) * DD + k0 + sk0;
    ushort8v b0 = *(const ushort8v*)(Bsrc + bbase);
    ushort8v b1 = *(const ushort8v*)(Bsrc + bbase + 8);
    __syncthreads();
    *(ushort8v*)&At[srow][sk0] = a0;
    *(ushort8v*)&At[srow][sk0 + 8] = a1;
    *(ushort8v*)&Bt[srow][sk0] = b0;
    *(ushort8v*)&Bt[srow][sk0 + 8] = b1;
    __syncthreads();

    bshort8 af[4], bfr[4];
#pragma unroll
    for (int i = 0; i < 4; ++i) {
      af[i] = *(const bshort8*)&At[wm + i * 16 + m16][quad * 8];
      bfr[i] = *(const bshort8*)&Bt[wn + i * 16 + m16][quad * 8];
    }
#pragma unroll
    for (int mi = 0; mi < 4; ++mi)
#pragma unroll
      for (int ni = 0; ni < 4; ++ni)
        acc[mi][ni] = __builtin_amdgcn_mfma_f32_16x16x32_bf16(
            af[mi], bfr[ni], acc[mi][ni], 0, 0, 0);
  }

  // epilogue: column cix -> plane p = cix>>9, dd = cix&511;
  // U4[(row*DD + dd)*4 + p]
#pragma unroll
  for (int mi = 0; mi < 4; ++mi) {
    int r0 = row0 + wm + mi * 16 + quad * 4;
#pragma unroll
    for (int ni = 0; ni < 4; ++ni) {
      int cix = col0 + wn + ni * 16 + m16;
      int p = cix >> 9;
      int dd = cix & 511;
#pragma unroll
      for (int reg = 0; reg < 4; ++reg)
        U4[((size_t)(r0 + reg) * DD + dd) * 4 + p] = acc[mi][ni][reg];
    }
  }
}

// ---- SRU scan, 8-deep prefetch, float4 U loads -------------------------
__global__ __launch_bounds__(64, 1)
void scan_kernel(const float* __restrict__ U4, float* __restrict__ X,
                 u16* __restrict__ Xh, u16* __restrict__ Xl,
                 const void* __restrict__ mask_p, const void* __restrict__ vbase,
                 const void* __restrict__ bbase, int layer,
                 const int* __restrict__ flags, float* __restrict__ carry,
                 int t0, int nt, int emit_hl) {
  __shared__ int msk[TT];
  int tid = threadIdx.x;
  int idx = blockIdx.x * 64 + tid;  // [0, B*D)
  int b = idx >> 9;
  int d = idx & 511;
  int ff = flags[0], fm = flags[1];

  const int* mi_ = (const int*)mask_p + b * TT;
  const unsigned char* mb_ = (const unsigned char*)mask_p + b * TT;
  for (int i = tid; i < nt; i += 64) msk[i] = fm ? (int)mb_[t0 + i] : mi_[t0 + i];
  __syncthreads();

  size_t voff = (size_t)layer * 2 * DD;
  float vf, vr, bf_, br_;
  if (ff) {
    const float* vp = (const float*)vbase + voff;
    const float* bp2 = (const float*)bbase + voff;
    vf = vp[d]; vr = vp[DD + d]; bf_ = bp2[d]; br_ = bp2[DD + d];
  } else {
    const u16* vp = (const u16*)vbase + voff;
    const u16* bp2 = (const u16*)bbase + voff;
    vf = b2f(vp[d]); vr = b2f(vp[DD + d]); bf_ = b2f(bp2[d]); br_ = b2f(bp2[DD + d]);
  }

  float c = (t0 == 0) ? 0.f : carry[idx];
  float* Xp = X + (size_t)b * TT * DD + d;
  const f32x4* Up = (const f32x4*)U4 + (size_t)b * DD + d;  // + t*BB*DD steps

  f32x4 pu[PF];
  float pi[PF];
#pragma unroll
  for (int j = 0; j < PF; ++j) {
    if (j < nt) {
      pu[j] = Up[(size_t)j * BB * DD];
      pi[j] = Xp[(size_t)(t0 + j) * DD];
    }
  }

  for (int tl0 = 0; tl0 < nt; tl0 += PF) {
#pragma unroll
    for (int j = 0; j < PF; ++j) {
      int tl = tl0 + j;
      f32x4 uv = pu[j];
      float xin = pi[j];
      int tn = tl + PF;
      if (tn < nt) {  // refill (c-independent, stays in flight PF iters)
        pu[j] = Up[(size_t)tn * BB * DD];
        pi[j] = Xp[(size_t)(t0 + tn) * DD];
      }
      int m = msk[tl];
      float zf = uv[1] + vf * c + bf_;
      float zr = uv[2] + vr * c + br_;
      float f = 1.f / (1.f + __expf(-zf));
      float r = 1.f / (1.f + __expf(-zr));
      float cn = f * c + (1.f - f) * uv[0];
      float e2 = __expf(2.f * cn);
      float th = (e2 - 1.f) / (e2 + 1.f);
      float h = r * th + (1.f - r) * xin;
      bool pad = (m == 0);
      if (!pad) c = cn;
      float hout = pad ? 0.f : h;
      int tg = t0 + tl;
      Xp[(size_t)tg * DD] = hout;
      if (emit_hl) {
        u16 hi = f2b(hout);
        size_t o = ((size_t)tg * BB + b) * DD + d;
        Xh[o] = hi;
        Xl[o] = f2b(hout - b2f(hi));
      }
    }
  }
  carry[idx] = c;
}

__global__ void sentinel_kernel(float* out) { out[threadIdx.x] = 12345.f; }

extern "C" void kernel_launch(void* const* d_in, const int* in_sizes, int n_in,
                              void* d_out, int out_size, void* d_ws, size_t ws_size,
                              hipStream_t stream) {
  const int* ids = (const int*)d_in[0];
  const void* mask = d_in[1];
  const void* emb = d_in[2];
  const void* W = d_in[3];
  const void* v = d_in[4];
  const void* bp = d_in[5];

  char* ws = (char*)d_ws;
  int* flags = (int*)ws;                      // 4 KiB
  float* carry = (float*)(ws + 4096);         // 64 KiB
  const size_t offXh = 69632;
  const size_t offXl = offXh + (size_t)MROWS * DD * 2;       // +16 MiB
  const size_t offWs = offXl + (size_t)MROWS * DD * 2;       // +16 MiB
  const size_t offU = offWs + (size_t)LAYERS * 2 * WPL * 2;  // +12 MiB
  const size_t perT = (size_t)BB * DD * 4 * 4;  // 262144 B / timestep (float4)

  const int cand[7] = {512, 256, 128, 64, 32, 16, 8};
  int chunkT = 0;
  for (int i = 0; i < 7; ++i) {
    if (ws_size >= offU + (size_t)cand[i] * perT) { chunkT = cand[i]; break; }
  }
  if (!chunkT) {
    sentinel_kernel<<<1, 256, 0, stream>>>((float*)d_out);
    return;
  }

  u16* Xh = (u16*)(ws + offXh);
  u16* Xl = (u16*)(ws + offXl);
  u16* Wst = (u16*)(ws + offWs);
  float* U4 = (float*)(ws + offU);
  float* X = (float*)d_out;  // (B,T,D) f32

  detect_kernel<<<1, 256, 0, stream>>>((const u16*)emb, (const int*)mask,
                                       (const int*)ids, flags);
  wprep_kernel<<<dim3(16, 48, 4), 256, 0, stream>>>(W, Wst, flags);
  embed_kernel<<<MROWS * DD / 256, 256, 0, stream>>>(ids, emb, X, Xh, Xl, flags);

  int nch = TT / chunkT;
  for (int l = 0; l < LAYERS; ++l) {
    const u16* Wsl = Wst + (size_t)l * 2 * WPL;
    for (int ch = 0; ch < nch; ++ch) {
      int t0 = ch * chunkT;
      dim3 g(chunkT * BB / 128, N3 / 128);
      gemm_kernel<<<g, 256, 0, stream>>>(Xh, Xl, Wsl, U4, t0 * BB);
      scan_kernel<<<BB * DD / 64, 64, 0, stream>>>(U4, X, Xh, Xl, mask, v, bp, l,
                                                   flags, carry, t0, chunkT,
                                                   (l < LAYERS - 1) ? 1 : 0);
    }
  }
}

// Round 7
// 961.738 us; speedup vs baseline: 1.8579x; 1.8579x over previous
//
#include <hip/hip_runtime.h>
#include <hip/hip_bf16.h>

// 4-layer SRU. L=4, B=32, T=512, D=512, V=1000. f32 inputs, f32 output.
// R6: GEMM reverted to R4 plane-layout (dense stores; U4 interleave caused
// partial-line RMW). Scan rewritten as branch-free PF=16 software pipeline:
// steady loop with unconditional refills + separate tail, emit as template.

#define LAYERS 4
#define BB 32
#define TT 512
#define DD 512
#define N3 1536
#define MROWS (TT * BB)
#define WPL ((size_t)DD * N3)   // 786432 elems per layer ([n][k] = 1536*512)
#define PF 16

typedef unsigned short u16;
typedef short bshort8 __attribute__((ext_vector_type(8)));
typedef unsigned short ushort8v __attribute__((ext_vector_type(8)));
typedef float f32x4 __attribute__((ext_vector_type(4)));

__device__ __forceinline__ float b2f(u16 u) {
  union { unsigned int i; float f; } x;
  x.i = ((unsigned int)u) << 16;
  return x.f;
}
__device__ __forceinline__ u16 f2b(float f) {  // RNE
  union { float f; unsigned int i; } x;
  x.f = f;
  unsigned int r = (x.i + 0x7FFFu + ((x.i >> 16) & 1u)) >> 16;
  return (u16)r;
}

// ---- dtype detection (flags[0]: floats f32, [1]: mask bytes, [2]: ids int64)
__global__ void detect_kernel(const u16* __restrict__ emb_u,
                              const int* __restrict__ mask_i,
                              const int* __restrict__ ids_i,
                              int* __restrict__ flags) {
  __shared__ int cnt[3];
  __shared__ int zc;
  int tid = threadIdx.x;
  if (tid < 3) cnt[tid] = 0;
  if (tid == 0) zc = 0;
  __syncthreads();
  int bad = 0, zero_even = 0;
  for (int i = tid; i < 8192; i += 256) {
    u16 u = emb_u[i];
    unsigned e = (u >> 7) & 0xFF;
    if (e >= 0x8F) bad++;
    if ((i & 1) == 0 && u == 0) zero_even++;
  }
  if (bad) atomicAdd(&cnt[0], bad);
  if (zero_even) atomicAdd(&zc, zero_even);
  if (tid < 64) {
    unsigned vv = (unsigned)mask_i[tid];
    if (vv > 1u) atomicAdd(&cnt[1], 1);
  }
  if (tid < 256) {
    if (ids_i[2 * tid + 1] == 0) atomicAdd(&cnt[2], 1);
  }
  __syncthreads();
  if (tid == 0) {
    flags[0] = (cnt[0] > 64 || zc > 3000) ? 1 : 0;
    flags[1] = (cnt[1] > 0) ? 1 : 0;
    flags[2] = (cnt[2] >= 192) ? 1 : 0;
  }
}

// ---- W split+transpose: Wst[l][s][n][k] bf16, s=0 hi, s=1 lo -----------
__global__ __launch_bounds__(256)
void wprep_kernel(const void* __restrict__ W, u16* __restrict__ Wst,
                  const int* __restrict__ flags) {
  __shared__ float tileW[32][33];
  int l = blockIdx.z;
  int k0 = blockIdx.x * 32;
  int n0 = blockIdx.y * 32;
  int tx = threadIdx.x & 31;
  int ty = threadIdx.x >> 5;  // 0..7
  int ff = flags[0];
  const float* Wf = (const float*)W + (size_t)l * WPL;
  const u16* Wb = (const u16*)W + (size_t)l * WPL;
  for (int kk = ty; kk < 32; kk += 8) {
    size_t off = (size_t)(k0 + kk) * N3 + n0 + tx;
    tileW[kk][tx] = ff ? Wf[off] : b2f(Wb[off]);
  }
  __syncthreads();
  u16* hiP = Wst + (size_t)l * 2 * WPL;
  u16* loP = hiP + WPL;
  for (int nn = ty; nn < 32; nn += 8) {
    float x = tileW[tx][nn];
    u16 hi = f2b(x);
    u16 lo = f2b(x - b2f(hi));
    size_t o = (size_t)(n0 + nn) * DD + k0 + tx;
    hiP[o] = hi;
    loP[o] = lo;
  }
}

// ---- embedding: X f32 (B,T,D) = d_out; Xh/Xl bf16 (T,B,D) --------------
__global__ void embed_kernel(const int* __restrict__ ids,
                             const void* __restrict__ emb,
                             float* __restrict__ X,
                             u16* __restrict__ Xh, u16* __restrict__ Xl,
                             const int* __restrict__ flags) {
  int i = blockIdx.x * 256 + threadIdx.x;  // (t,b,d) linear
  int d = i & (DD - 1);
  int tb = i >> 9;
  int b = tb & (BB - 1);
  int t = tb >> 5;
  int ii = b * TT + t;
  int id = flags[2] ? ids[2 * ii] : ids[ii];
  float val = flags[0] ? ((const float*)emb)[id * DD + d]
                       : b2f(((const u16*)emb)[id * DD + d]);
  X[((size_t)b * TT + t) * DD + d] = val;
  u16 hi = f2b(val);
  Xh[i] = hi;
  Xl[i] = f2b(val - b2f(hi));
}

// ---- MFMA GEMM: U[chunkM,1536] = split-f32 X[row_base..]*W_l (R4 ver) --
__global__ __launch_bounds__(256)
void gemm_kernel(const u16* __restrict__ Xh, const u16* __restrict__ Xl,
                 const u16* __restrict__ Ws,  // layer base [2][1536][512]
                 float* __restrict__ U, int row_base) {
  __shared__ u16 At[128][40];
  __shared__ u16 Bt[128][40];
  const int tid = threadIdx.x;
  const int row0 = blockIdx.x * 128;
  const int col0 = blockIdx.y * 128;
  const int lane = tid & 63, wave = tid >> 6;
  const int wm = (wave >> 1) * 64, wn = (wave & 1) * 64;
  const int m16 = lane & 15, quad = lane >> 4;
  const int srow = tid >> 1;
  const int sk0 = (tid & 1) * 16;

  f32x4 acc[4][4];
#pragma unroll
  for (int mi = 0; mi < 4; ++mi)
#pragma unroll
    for (int ni = 0; ni < 4; ++ni)
#pragma unroll
      for (int r = 0; r < 4; ++r) acc[mi][ni][r] = 0.f;

  for (int kv = 0; kv < 1536; kv += 32) {
    int p = kv >> 9;
    int k0 = kv & 511;
    const u16* Asrc = (p == 2) ? Xl : Xh;
    const u16* Bsrc = Ws + ((p == 1) ? WPL : 0);

    size_t abase = (size_t)(row_base + row0 + srow) * DD + k0 + sk0;
    ushort8v a0 = *(const ushort8v*)(Asrc + abase);
    ushort8v a1 = *(const ushort8v*)(Asrc + abase + 8);
    size_t bbase = (size_t)(col0 + srow) * DD + k0 + sk0;
    ushort8v b0 = *(const ushort8v*)(Bsrc + bbase);
    ushort8v b1 = *(const ushort8v*)(Bsrc + bbase + 8);
    __syncthreads();
    *(ushort8v*)&At[srow][sk0] = a0;
    *(ushort8v*)&At[srow][sk0 + 8] = a1;
    *(ushort8v*)&Bt[srow][sk0] = b0;
    *(ushort8v*)&Bt[srow][sk0 + 8] = b1;
    __syncthreads();

    bshort8 af[4], bfr[4];
#pragma unroll
    for (int i = 0; i < 4; ++i) {
      af[i] = *(const bshort8*)&At[wm + i * 16 + m16][quad * 8];
      bfr[i] = *(const bshort8*)&Bt[wn + i * 16 + m16][quad * 8];
    }
#pragma unroll
    for (int mi = 0; mi < 4; ++mi)
#pragma unroll
      for (int ni = 0; ni < 4; ++ni)
        acc[mi][ni] = __builtin_amdgcn_mfma_f32_16x16x32_bf16(
            af[mi], bfr[ni], acc[mi][ni], 0, 0, 0);
  }

#pragma unroll
  for (int mi = 0; mi < 4; ++mi) {
    int r0 = row0 + wm + mi * 16 + quad * 4;
#pragma unroll
    for (int ni = 0; ni < 4; ++ni) {
      int cix = col0 + wn + ni * 16 + m16;
#pragma unroll
      for (int reg = 0; reg < 4; ++reg)
        U[(size_t)(r0 + reg) * N3 + cix] = acc[mi][ni][reg];
    }
  }
}

// ---- SRU scan: branch-free PF-deep pipeline ----------------------------
template <int EMIT>
__global__ __launch_bounds__(64, 1)
void scan_kernel(const float* __restrict__ U, float* __restrict__ X,
                 u16* __restrict__ Xh, u16* __restrict__ Xl,
                 const void* __restrict__ mask_p, const void* __restrict__ vbase,
                 const void* __restrict__ bbase, int layer,
                 const int* __restrict__ flags, float* __restrict__ carry,
                 int t0, int nt) {
  __shared__ int msk[TT];
  int tid = threadIdx.x;
  int idx = blockIdx.x * 64 + tid;  // [0, B*D)
  int b = idx >> 9;
  int d = idx & 511;
  int ff = flags[0], fm = flags[1];

  const int* mi_ = (const int*)mask_p + b * TT;
  const unsigned char* mb_ = (const unsigned char*)mask_p + b * TT;
  for (int i = tid; i < nt; i += 64) msk[i] = fm ? (int)mb_[t0 + i] : mi_[t0 + i];
  __syncthreads();

  size_t voff = (size_t)layer * 2 * DD;
  float vf, vr, bf_, br_;
  if (ff) {
    const float* vp = (const float*)vbase + voff;
    const float* bp2 = (const float*)bbase + voff;
    vf = vp[d]; vr = vp[DD + d]; bf_ = bp2[d]; br_ = bp2[DD + d];
  } else {
    const u16* vp = (const u16*)vbase + voff;
    const u16* bp2 = (const u16*)bbase + voff;
    vf = b2f(vp[d]); vr = b2f(vp[DD + d]); bf_ = b2f(bp2[d]); br_ = b2f(bp2[DD + d]);
  }

  float c = (t0 == 0) ? 0.f : carry[idx];
  float* Xp = X + (size_t)b * TT * DD + d;          // + t*DD
  const float* Ub = U + (size_t)b * N3 + d;         // + tl*BB*N3, planes +512/+1024

  auto step = [&](int tl_, float xt, float fp, float rp, float xin) {
    int m = msk[tl_];
    float zf = fp + vf * c + bf_;
    float zr = rp + vr * c + br_;
    float f = 1.f / (1.f + __expf(-zf));
    float r = 1.f / (1.f + __expf(-zr));
    float cn = f * c + (1.f - f) * xt;
    float e2 = __expf(2.f * cn);
    float th = (e2 - 1.f) / (e2 + 1.f);
    float h = r * th + (1.f - r) * xin;
    bool pad = (m == 0);
    c = pad ? c : cn;
    float hout = pad ? 0.f : h;
    int tg = t0 + tl_;
    Xp[(size_t)tg * DD] = hout;
    if (EMIT) {
      u16 hi = f2b(hout);
      size_t o = ((size_t)tg * BB + b) * DD + d;
      Xh[o] = hi;
      Xl[o] = f2b(hout - b2f(hi));
    }
  };

  float px[PF], pf_[PF], pr[PF], pi[PF];
#pragma unroll
  for (int j = 0; j < PF; ++j) {
    const float* u = Ub + (size_t)j * BB * N3;
    px[j] = u[0];
    pf_[j] = u[512];
    pr[j] = u[1024];
    pi[j] = Xp[(size_t)(t0 + j) * DD];
  }

  int tl = 0;
  for (; tl + 2 * PF <= nt; tl += PF) {
#pragma unroll
    for (int j = 0; j < PF; ++j) {
      float xt = px[j], fp = pf_[j], rp = pr[j], xin = pi[j];
      // unconditional refill for step tl+j+PF (kept PF steps in flight)
      const float* u = Ub + (size_t)(tl + j + PF) * BB * N3;
      px[j] = u[0];
      pf_[j] = u[512];
      pr[j] = u[1024];
      pi[j] = Xp[(size_t)(t0 + tl + j + PF) * DD];
      step(tl + j, xt, fp, rp, xin);
    }
  }
  // tail: final PF steps, no refills (nt is a multiple of PF, nt >= 2*PF)
#pragma unroll
  for (int j = 0; j < PF; ++j) {
    step(tl + j, px[j], pf_[j], pr[j], pi[j]);
  }
  carry[idx] = c;
}

__global__ void sentinel_kernel(float* out) { out[threadIdx.x] = 12345.f; }

extern "C" void kernel_launch(void* const* d_in, const int* in_sizes, int n_in,
                              void* d_out, int out_size, void* d_ws, size_t ws_size,
                              hipStream_t stream) {
  const int* ids = (const int*)d_in[0];
  const void* mask = d_in[1];
  const void* emb = d_in[2];
  const void* W = d_in[3];
  const void* v = d_in[4];
  const void* bp = d_in[5];

  char* ws = (char*)d_ws;
  int* flags = (int*)ws;                      // 4 KiB
  float* carry = (float*)(ws + 4096);         // 64 KiB
  const size_t offXh = 69632;
  const size_t offXl = offXh + (size_t)MROWS * DD * 2;       // +16 MiB
  const size_t offWs = offXl + (size_t)MROWS * DD * 2;       // +16 MiB
  const size_t offU = offWs + (size_t)LAYERS * 2 * WPL * 2;  // +12 MiB
  const size_t perT = (size_t)BB * N3 * 4;    // 196608 B / timestep

  const int cand[5] = {512, 256, 128, 64, 32};  // all multiples of 2*PF
  int chunkT = 0;
  for (int i = 0; i < 5; ++i) {
    if (ws_size >= offU + (size_t)cand[i] * perT) { chunkT = cand[i]; break; }
  }
  if (!chunkT) {
    sentinel_kernel<<<1, 256, 0, stream>>>((float*)d_out);
    return;
  }

  u16* Xh = (u16*)(ws + offXh);
  u16* Xl = (u16*)(ws + offXl);
  u16* Wst = (u16*)(ws + offWs);
  float* U = (float*)(ws + offU);
  float* X = (float*)d_out;  // (B,T,D) f32

  detect_kernel<<<1, 256, 0, stream>>>((const u16*)emb, (const int*)mask,
                                       (const int*)ids, flags);
  wprep_kernel<<<dim3(16, 48, 4), 256, 0, stream>>>(W, Wst, flags);
  embed_kernel<<<MROWS * DD / 256, 256, 0, stream>>>(ids, emb, X, Xh, Xl, flags);

  int nch = TT / chunkT;
  for (int l = 0; l < LAYERS; ++l) {
    const u16* Wsl = Wst + (size_t)l * 2 * WPL;
    for (int ch = 0; ch < nch; ++ch) {
      int t0 = ch * chunkT;
      dim3 g(chunkT * BB / 128, N3 / 128);
      gemm_kernel<<<g, 256, 0, stream>>>(Xh, Xl, Wsl, U, t0 * BB);
      if (l < LAYERS - 1)
        scan_kernel<1><<<BB * DD / 64, 64, 0, stream>>>(U, X, Xh, Xl, mask, v, bp,
                                                        l, flags, carry, t0, chunkT);
      else
        scan_kernel<0><<<BB * DD / 64, 64, 0, stream>>>(U, X, Xh, Xl, mask, v, bp,
                                                        l, flags, carry, t0, chunkT);
    }
  }
}